// Round 5
// baseline (1456.175 us; speedup 1.0000x reference)
//
#include <hip/hip_runtime.h>
#include <stdint.h>
#include <math.h>

// Problem constants (B, CK, CV, T, H, W) = (4, 64, 512, 8, 32, 32)
#define NB   4
#define CK   64
#define CV   512
#define THW  8192
#define HW   1024
#define MDRAW 4096   // floor(THW * 0.5)
#define NTC  32      // t-chunks for stats pass (8192/32 = 256 t per chunk)

// ---- ws layout (float offsets) ----
#define OFF_QKBAR 0                      // NB*CK            = 256
#define OFF_A     (OFF_QKBAR + NB*CK)    // NB*THW           = 32768
#define OFF_MASK  (OFF_A + NB*THW)       // NB*THW
#define OFF_MULT  (OFF_MASK + NB*THW)    // NB*THW
#define OFF_PM    (OFF_MULT + NB*THW)    // NB*HW*NTC        = 131072
#define OFF_PL    (OFF_PM + NB*HW*NTC)   // NB*HW*NTC
#define OFF_MF    (OFF_PL + NB*HW*NTC)   // NB*HW
#define OFF_LI    (OFF_MF + NB*HW)       // NB*HW
// total = 368896 floats (~1.41 MB)

// ---------------- K1: qkbar[b][c] = mean_q qk[b][c][q] (f64 accumulate) ----------------
__global__ __launch_bounds__(256) void qkbar_kernel(const float* __restrict__ qk,
                                                    float* __restrict__ qkbar) {
  int bc = blockIdx.x;                       // b*64 + c, 256 blocks
  const float4* src = (const float4*)(qk + (size_t)bc * HW);
  float4 v = src[threadIdx.x];
  double s = (double)v.x + (double)v.y + (double)v.z + (double)v.w;
  __shared__ double red[256];
  red[threadIdx.x] = s; __syncthreads();
  for (int st = 128; st > 0; st >>= 1) {
    if (threadIdx.x < st) red[threadIdx.x] += red[threadIdx.x + st];
    __syncthreads();
  }
  if (threadIdx.x == 0) qkbar[bc] = (float)(red[0] * (1.0 / 1024.0));
}

// ------- K2: a[t] = ||mk_t||^2 ; masked[t] = (mask>0.5) ? support : 0 ; mult=1 -------
// f64 accumulation so the sort key error is at the reference's own f32-rounding floor.
__global__ __launch_bounds__(256) void support_kernel(const float* __restrict__ mk,
                                                      const float* __restrict__ mask,
                                                      const float* __restrict__ qkbar,
                                                      float* __restrict__ amem,
                                                      float* __restrict__ masked,
                                                      float* __restrict__ mult) {
  int b = blockIdx.y;
  int t = blockIdx.x * 256 + threadIdx.x;    // 32 x-blocks
  __shared__ float qb[CK];
  if (threadIdx.x < CK) qb[threadIdx.x] = qkbar[b * CK + threadIdx.x];
  __syncthreads();
  const float* mkp = mk + (size_t)b * CK * THW + t;
  double a = 0.0, d = 0.0;
  #pragma unroll
  for (int c = 0; c < CK; c++) {
    double v = (double)mkp[(size_t)c * THW];
    a += v * v;
    d += v * (double)qb[c];
  }
  double sup = (2.0 * d - a) * 0.125;        // (-a + 2*mk.qkbar)/sqrt(64)
  amem[b * THW + t] = (float)a;
  float mval = mask[b * THW + t];
  masked[b * THW + t] = (mval > 0.5f) ? (float)sup : 0.0f;
  mult[b * THW + t] = 1.0f;
}

// ---------------- Threefry-2x32-20, key = (0, 1234) — matches jax.random.key(1234) ----------------
__device__ __forceinline__ uint32_t rotl32(uint32_t v, int d) {
  return (v << d) | (v >> (32 - d));
}
__device__ __forceinline__ void tf2x32(uint32_t& x0, uint32_t& x1) {
  const uint32_t ks0 = 0u, ks1 = 1234u;
  const uint32_t ks2 = ks0 ^ ks1 ^ 0x1BD11BDAu;
  x0 += ks0; x1 += ks1;
#define TF_R4(ra,rb,rc,rd) \
  x0 += x1; x1 = rotl32(x1, ra); x1 ^= x0; \
  x0 += x1; x1 = rotl32(x1, rb); x1 ^= x0; \
  x0 += x1; x1 = rotl32(x1, rc); x1 ^= x0; \
  x0 += x1; x1 = rotl32(x1, rd); x1 ^= x0;
  TF_R4(13,15,26,6);  x0 += ks1; x1 += ks2 + 1u;
  TF_R4(17,29,16,24); x0 += ks2; x1 += ks0 + 2u;
  TF_R4(13,15,26,6);  x0 += ks0; x1 += ks1 + 3u;
  TF_R4(17,29,16,24); x0 += ks1; x1 += ks2 + 4u;
  TF_R4(13,15,26,6);  x0 += ks2; x1 += ks0 + 5u;
#undef TF_R4
}

// ------- K3: per-batch bitonic sort (desc, idx-asc ties) + threefry draws + mult scatter -------
// LDS: 32KB key + 16KB ushort idx + 8KB reductions = 56KB (< 64KB, safe everywhere)
__global__ __launch_bounds__(1024) void sort_realloc_kernel(const float* __restrict__ masked,
                                                            float* __restrict__ mult) {
  int b = blockIdx.x;
  int tid = threadIdx.x;
  __shared__ float key[THW];
  __shared__ unsigned short kidx[THW];
  __shared__ float redF[1024];
  __shared__ int   redI[1024];

  int nz = 0;
  for (int i = tid; i < THW; i += 1024) {
    float v = masked[b * THW + i];
    key[i] = v; kidx[i] = (unsigned short)i;
    if (v != 0.0f) nz++;
  }
  redI[tid] = nz;
  // bitonic sort: descending by value, ascending index on ties (== stable argsort of -masked)
  for (int kk = 2; kk <= THW; kk <<= 1) {
    for (int j = kk >> 1; j > 0; j >>= 1) {
      __syncthreads();
      for (int i = tid; i < THW; i += 1024) {
        int l = i ^ j;
        if (l > i) {
          float av = key[i], bv = key[l];
          unsigned short ia = kidx[i], ib = kidx[l];
          bool before = (av > bv) || (av == bv && ia < ib);
          bool up = ((i & kk) == 0);
          if (up ? !before : before) {
            key[i] = bv; key[l] = av; kidx[i] = ib; kidx[l] = ia;
          }
        }
      }
    }
  }
  __syncthreads();
  // reduce nz -> k
  for (int st = 512; st > 0; st >>= 1) {
    if (tid < st) redI[tid] += redI[tid + st];
    __syncthreads();
  }
  int kcnt = redI[0];
  float kf = (float)kcnt;
  int n_sel = (int)floorf(kf * 0.5f);

  // draws: m = tid + r*1024, element e = b*4096 + m of the flat (4,4096) uniform.
  // JAX threefry_partitionable path (default-on in modern JAX): per-element
  // counter = 64-bit flat index -> (hi, lo) = (0, e); 32-bit draw = out0 ^ out1.
  float wsel[4]; int rowv[4]; bool vld[4];
  float ssum = 0.f;
  #pragma unroll
  for (int r = 0; r < 4; r++) {
    int m = tid + r * 1024;
    uint32_t e = (uint32_t)(b * MDRAW + m);
    uint32_t x0 = 0u, x1 = e;
    tf2x32(x0, x1);
    uint32_t bits = x0 ^ x1;
    float u = __uint_as_float((bits >> 9) | 0x3F800000u) - 1.0f;
    int idxd = (int)floorf(u * kf);          // bit-exact vs jnp.floor(u*kf) in f32
    vld[r] = (m < n_sel);
    wsel[r] = (float)(idxd + 1);
    rowv[r] = (int)kidx[idxd < THW ? idxd : (THW - 1)];
    if (vld[r]) ssum += wsel[r];   // integer-valued; total < 2^24 -> exact, order-free
  }
  redF[tid] = ssum;
  __syncthreads();
  for (int st = 512; st > 0; st >>= 1) {
    if (tid < st) redF[tid] += redF[tid + st];
    __syncthreads();
  }
  float s = redF[0];
  s = (s > 0.f) ? s : 1.0f;
  #pragma unroll
  for (int r = 0; r < 4; r++) {
    if (vld[r]) {
      float wi = wsel[r] * kf / s;
      mult[b * THW + rowv[r]] = wi;   // duplicate rows write identical values
    }
  }
}

// ------- K4: softmax stats (partial max / sumexp per t-chunk), logits on the fly -------
__global__ __launch_bounds__(256) void stats_kernel(const float* __restrict__ mk,
                                                    const float* __restrict__ qk,
                                                    const float* __restrict__ amem,
                                                    const float* __restrict__ mult,
                                                    float* __restrict__ pm,
                                                    float* __restrict__ pl) {
  int b = blockIdx.z, tc = blockIdx.y, qb = blockIdx.x;
  int tid = threadIdx.x;
  int q = qb * 256 + tid;
  __shared__ float mk_sT[64][68];    // [t][c]; float4 rows stay 16B-aligned (68*4=272=16*17)
  __shared__ float am_s[64], mu_s[64];
  float qreg[CK];
  #pragma unroll
  for (int c = 0; c < CK; c++) qreg[c] = qk[((size_t)b * CK + c) * HW + q];

  float m_run = -INFINITY, l_run = 0.f;
  int tbase = tc * (THW / NTC);      // 256 t per chunk, staged 64 at a time
  for (int ss = 0; ss < 4; ss++) {
    int t0 = tbase + ss * 64;
    __syncthreads();
    for (int l = tid; l < 64 * 64; l += 256) {
      int c = l >> 6, i = l & 63;
      mk_sT[i][c] = mk[((size_t)b * CK + c) * THW + t0 + i];
    }
    if (tid < 64) {
      am_s[tid] = amem[b * THW + t0 + tid];
      mu_s[tid] = mult[b * THW + t0 + tid];
    }
    __syncthreads();
    for (int t = 0; t < 64; t++) {
      float d = 0.f;
      #pragma unroll
      for (int cc = 0; cc < CK; cc += 4) {
        float4 m4 = *(const float4*)&mk_sT[t][cc];   // broadcast across lanes
        d += m4.x * qreg[cc] + m4.y * qreg[cc + 1] + m4.z * qreg[cc + 2] + m4.w * qreg[cc + 3];
      }
      float L = mu_s[t] * ((2.0f * d - am_s[t]) * 0.125f);
      if (L > m_run) { l_run *= expf(m_run - L); m_run = L; }
      l_run += expf(L - m_run);
    }
  }
  int o = (b * HW + q) * NTC + tc;
  pm[o] = m_run; pl[o] = l_run;
}

// ------- K5: combine partial stats -> final max, 1/sumexp -------
__global__ __launch_bounds__(256) void combine_kernel(const float* __restrict__ pm,
                                                      const float* __restrict__ pl,
                                                      float* __restrict__ mfin,
                                                      float* __restrict__ linv) {
  int i = blockIdx.x * 256 + threadIdx.x;    // over NB*HW = 4096
  const float* pmi = pm + (size_t)i * NTC;
  const float* pli = pl + (size_t)i * NTC;
  float m = -INFINITY;
  for (int c = 0; c < NTC; c++) m = fmaxf(m, pmi[c]);
  float l = 0.f;
  for (int c = 0; c < NTC; c++) l += pli[c] * expf(pmi[c] - m);
  mfin[i] = m; linv[i] = 1.0f / l;
}

// ------- K6: fused logit-recompute + softmax-normalize + PV GEMM -------
// grid (qt=16, ct=4, b=4), 512 threads. QT=64 queries, CT=128 channels per block.
#define QT 64
#define CT 128
__global__ __launch_bounds__(512) void pv_kernel(const float* __restrict__ mk,
                                                 const float* __restrict__ qk,
                                                 const float* __restrict__ mv,
                                                 const float* __restrict__ amem,
                                                 const float* __restrict__ mult,
                                                 const float* __restrict__ mfin,
                                                 const float* __restrict__ linv,
                                                 float* __restrict__ out) {
  int b = blockIdx.z, ct = blockIdx.y, qt = blockIdx.x;
  int tid = threadIdx.x;

  __shared__ float qk_s[CK][QT];         // 16 KB
  __shared__ float mk_s[CK][64];         // 16 KB  [c][t]
  __shared__ float P_s[64][68];          // 17 KB  [t][q], padded (272B rows, 16B-aligned)
  __shared__ float mv_s[CT][65];         // 33 KB  [c][t], padded
  __shared__ float am_s[64], mu_s[64];
  __shared__ float ms_s[QT], ls_s[QT];

  const int q0blk = qt * QT;
  for (int l = tid; l < CK * QT; l += 512) {
    int c = l / QT, q = l % QT;
    qk_s[c][q] = qk[((size_t)b * CK + c) * HW + q0blk + q];
  }
  if (tid < QT) {
    ms_s[tid] = mfin[b * HW + q0blk + tid];
    ls_s[tid] = linv[b * HW + q0blk + tid];
  }

  float acc[16];
  #pragma unroll
  for (int i = 0; i < 16; i++) acc[i] = 0.f;

  const int tA = tid >> 3, qoA = (tid & 7) * 8;         // phase A: 64 t x 8 q-octets
  const int q0B = (tid & 15) * 4, c0B = (tid >> 4) * 4; // phase B: 4c x 4q per thread

  for (int t0 = 0; t0 < THW; t0 += 64) {
    __syncthreads();
    // stage mk [64c][64t] and mv [128c][64t]
    for (int l = tid; l < CK * 64; l += 512) {
      int c = l >> 6, i = l & 63;
      mk_s[c][i] = mk[((size_t)b * CK + c) * THW + t0 + i];
    }
    for (int l = tid; l < CT * 64; l += 512) {
      int c = l >> 6, i = l & 63;
      mv_s[c][i] = mv[((size_t)b * CV + ct * CT + c) * THW + t0 + i];
    }
    if (tid < 64) {
      am_s[tid] = amem[b * THW + t0 + tid];
      mu_s[tid] = mult[b * THW + t0 + tid];
    }
    __syncthreads();

    // phase A: logits -> normalized P
    {
      float d[8] = {0,0,0,0,0,0,0,0};
      #pragma unroll 16
      for (int c = 0; c < CK; c++) {
        float mkv = mk_s[c][tA];
        float4 qa = *(const float4*)&qk_s[c][qoA];
        float4 qb = *(const float4*)&qk_s[c][qoA + 4];
        d[0] += mkv * qa.x; d[1] += mkv * qa.y; d[2] += mkv * qa.z; d[3] += mkv * qa.w;
        d[4] += mkv * qb.x; d[5] += mkv * qb.y; d[6] += mkv * qb.z; d[7] += mkv * qb.w;
      }
      float a = am_s[tA], mu = mu_s[tA];
      float4 pA, pB;
      float L;
      L = mu * ((2.0f*d[0] - a) * 0.125f); pA.x = expf(L - ms_s[qoA+0]) * ls_s[qoA+0];
      L = mu * ((2.0f*d[1] - a) * 0.125f); pA.y = expf(L - ms_s[qoA+1]) * ls_s[qoA+1];
      L = mu * ((2.0f*d[2] - a) * 0.125f); pA.z = expf(L - ms_s[qoA+2]) * ls_s[qoA+2];
      L = mu * ((2.0f*d[3] - a) * 0.125f); pA.w = expf(L - ms_s[qoA+3]) * ls_s[qoA+3];
      L = mu * ((2.0f*d[4] - a) * 0.125f); pB.x = expf(L - ms_s[qoA+4]) * ls_s[qoA+4];
      L = mu * ((2.0f*d[5] - a) * 0.125f); pB.y = expf(L - ms_s[qoA+5]) * ls_s[qoA+5];
      L = mu * ((2.0f*d[6] - a) * 0.125f); pB.z = expf(L - ms_s[qoA+6]) * ls_s[qoA+6];
      L = mu * ((2.0f*d[7] - a) * 0.125f); pB.w = expf(L - ms_s[qoA+7]) * ls_s[qoA+7];
      *(float4*)&P_s[tA][qoA]     = pA;
      *(float4*)&P_s[tA][qoA + 4] = pB;
    }
    __syncthreads();

    // phase B: acc[c][q] += mv[c][t] * P[t][q]
    #pragma unroll 8
    for (int t = 0; t < 64; t++) {
      float4 p4 = *(const float4*)&P_s[t][q0B];
      float m0 = mv_s[c0B + 0][t];
      float m1 = mv_s[c0B + 1][t];
      float m2 = mv_s[c0B + 2][t];
      float m3 = mv_s[c0B + 3][t];
      acc[0]  += m0 * p4.x; acc[1]  += m0 * p4.y; acc[2]  += m0 * p4.z; acc[3]  += m0 * p4.w;
      acc[4]  += m1 * p4.x; acc[5]  += m1 * p4.y; acc[6]  += m1 * p4.z; acc[7]  += m1 * p4.w;
      acc[8]  += m2 * p4.x; acc[9]  += m2 * p4.y; acc[10] += m2 * p4.z; acc[11] += m2 * p4.w;
      acc[12] += m3 * p4.x; acc[13] += m3 * p4.y; acc[14] += m3 * p4.z; acc[15] += m3 * p4.w;
    }
  }

  #pragma unroll
  for (int i = 0; i < 4; i++) {
    float4 o4 = make_float4(acc[i*4+0], acc[i*4+1], acc[i*4+2], acc[i*4+3]);
    *(float4*)&out[((size_t)b * 1024 + ct * CT + c0B + i) * HW + q0blk + q0B] = o4;
  }
}

// ------- K7: qv passthrough into out[:, 512:1024] -------
__global__ __launch_bounds__(256) void qvcopy_kernel(const float* __restrict__ qv,
                                                     float* __restrict__ out) {
  int i = blockIdx.x * 256 + threadIdx.x;   // over NB*CV*HW/4 = 524288 float4s
  const float4* src = (const float4*)qv;
  float4* dst = (float4*)out;
  int q4 = i & 255;
  int c = (i >> 8) & 511;
  int b = i >> 17;
  dst[((size_t)(b * 1024 + 512 + c) << 8) + q4] = src[i];
}

extern "C" void kernel_launch(void* const* d_in, const int* in_sizes, int n_in,
                              void* d_out, int out_size, void* d_ws, size_t ws_size,
                              hipStream_t stream) {
  (void)in_sizes; (void)n_in; (void)out_size; (void)ws_size;
  const float* mk   = (const float*)d_in[0];
  const float* qk   = (const float*)d_in[1];
  const float* mv   = (const float*)d_in[2];
  const float* qv   = (const float*)d_in[3];
  const float* mask = (const float*)d_in[4];
  float* out = (float*)d_out;
  float* W = (float*)d_ws;

  float* qkbar  = W + OFF_QKBAR;
  float* amem   = W + OFF_A;
  float* masked = W + OFF_MASK;
  float* mult   = W + OFF_MULT;
  float* pm     = W + OFF_PM;
  float* pl     = W + OFF_PL;
  float* mfin   = W + OFF_MF;
  float* linv   = W + OFF_LI;

  qkbar_kernel<<<NB * CK, 256, 0, stream>>>(qk, qkbar);
  support_kernel<<<dim3(THW / 256, NB), 256, 0, stream>>>(mk, mask, qkbar, amem, masked, mult);
  sort_realloc_kernel<<<NB, 1024, 0, stream>>>(masked, mult);
  stats_kernel<<<dim3(HW / 256, NTC, NB), 256, 0, stream>>>(mk, qk, amem, mult, pm, pl);
  combine_kernel<<<NB * HW / 256, 256, 0, stream>>>(pm, pl, mfin, linv);
  pv_kernel<<<dim3(HW / QT, CV / CT, NB), 512, 0, stream>>>(mk, qk, mv, amem, mult, mfin, linv, out);
  qvcopy_kernel<<<NB * CV * HW / 4 / 256, 256, 0, stream>>>(qv, out);
}

// Round 6
// 806.030 us; speedup vs baseline: 1.8066x; 1.8066x over previous
//
#include <hip/hip_runtime.h>
#include <hip/hip_fp16.h>
#include <stdint.h>
#include <math.h>

// Problem constants (B, CK, CV, T, H, W) = (4, 64, 512, 8, 32, 32)
#define NB   4
#define CK   64
#define CV   512
#define THW  8192
#define HW   1024
#define MDRAW 4096   // floor(THW * 0.5)
#define NTC  32      // t-chunks for stats pass (8192/32 = 256 t per chunk)

// ---- ws layout (float offsets) ----
#define OFF_QKBAR 0                      // NB*CK            = 256
#define OFF_A     (OFF_QKBAR + NB*CK)    // NB*THW           = 32768
#define OFF_MASK  (OFF_A + NB*THW)       // NB*THW
#define OFF_MULT  (OFF_MASK + NB*THW)    // NB*THW
#define OFF_PM    (OFF_MULT + NB*THW)    // NB*HW*NTC        = 131072
#define OFF_PL    (OFF_PM + NB*HW*NTC)   // NB*HW*NTC
#define OFF_MF    (OFF_PL + NB*HW*NTC)   // NB*HW
#define OFF_LI    (OFF_MF + NB*HW)       // NB*HW
#define WS_FLOATS (OFF_LI + NB*HW)       // 368896 floats
#define OFF_P_BYTES ((size_t)WS_FLOATS * 4)            // 1475584 (16B aligned)
#define P_BYTES   ((size_t)NB * HW * THW * 2)          // 64 MiB f16
#define WS_NEED   (OFF_P_BYTES + P_BYTES)

typedef _Float16 half8 __attribute__((ext_vector_type(8)));
typedef float f32x4 __attribute__((ext_vector_type(4)));

// ---------------- K1: qkbar[b][c] = mean_q qk[b][c][q] (f64 accumulate) ----------------
__global__ __launch_bounds__(256) void qkbar_kernel(const float* __restrict__ qk,
                                                    float* __restrict__ qkbar) {
  int bc = blockIdx.x;
  const float4* src = (const float4*)(qk + (size_t)bc * HW);
  float4 v = src[threadIdx.x];
  double s = (double)v.x + (double)v.y + (double)v.z + (double)v.w;
  __shared__ double red[256];
  red[threadIdx.x] = s; __syncthreads();
  for (int st = 128; st > 0; st >>= 1) {
    if (threadIdx.x < st) red[threadIdx.x] += red[threadIdx.x + st];
    __syncthreads();
  }
  if (threadIdx.x == 0) qkbar[bc] = (float)(red[0] * (1.0 / 1024.0));
}

// ------- K2: a[t] = ||mk_t||^2 ; masked[t] = (mask>0.5) ? support : 0 ; mult=1 -------
__global__ __launch_bounds__(256) void support_kernel(const float* __restrict__ mk,
                                                      const float* __restrict__ mask,
                                                      const float* __restrict__ qkbar,
                                                      float* __restrict__ amem,
                                                      float* __restrict__ masked,
                                                      float* __restrict__ mult) {
  int b = blockIdx.y;
  int t = blockIdx.x * 256 + threadIdx.x;
  __shared__ float qb[CK];
  if (threadIdx.x < CK) qb[threadIdx.x] = qkbar[b * CK + threadIdx.x];
  __syncthreads();
  const float* mkp = mk + (size_t)b * CK * THW + t;
  double a = 0.0, d = 0.0;
  #pragma unroll
  for (int c = 0; c < CK; c++) {
    double v = (double)mkp[(size_t)c * THW];
    a += v * v;
    d += v * (double)qb[c];
  }
  double sup = (2.0 * d - a) * 0.125;
  amem[b * THW + t] = (float)a;
  float mval = mask[b * THW + t];
  masked[b * THW + t] = (mval > 0.5f) ? (float)sup : 0.0f;
  mult[b * THW + t] = 1.0f;
}

// ---------------- Threefry-2x32-20, key = (0, 1234) ----------------
__device__ __forceinline__ uint32_t rotl32(uint32_t v, int d) {
  return (v << d) | (v >> (32 - d));
}
__device__ __forceinline__ void tf2x32(uint32_t& x0, uint32_t& x1) {
  const uint32_t ks0 = 0u, ks1 = 1234u;
  const uint32_t ks2 = ks0 ^ ks1 ^ 0x1BD11BDAu;
  x0 += ks0; x1 += ks1;
#define TF_R4(ra,rb,rc,rd) \
  x0 += x1; x1 = rotl32(x1, ra); x1 ^= x0; \
  x0 += x1; x1 = rotl32(x1, rb); x1 ^= x0; \
  x0 += x1; x1 = rotl32(x1, rc); x1 ^= x0; \
  x0 += x1; x1 = rotl32(x1, rd); x1 ^= x0;
  TF_R4(13,15,26,6);  x0 += ks1; x1 += ks2 + 1u;
  TF_R4(17,29,16,24); x0 += ks2; x1 += ks0 + 2u;
  TF_R4(13,15,26,6);  x0 += ks0; x1 += ks1 + 3u;
  TF_R4(17,29,16,24); x0 += ks1; x1 += ks2 + 4u;
  TF_R4(13,15,26,6);  x0 += ks2; x1 += ks0 + 5u;
#undef TF_R4
}

// ------- K3: per-batch bitonic sort + threefry (partitionable mode) + mult scatter -------
__global__ __launch_bounds__(1024) void sort_realloc_kernel(const float* __restrict__ masked,
                                                            float* __restrict__ mult) {
  int b = blockIdx.x;
  int tid = threadIdx.x;
  __shared__ float key[THW];
  __shared__ unsigned short kidx[THW];
  __shared__ float redF[1024];
  __shared__ int   redI[1024];

  int nz = 0;
  for (int i = tid; i < THW; i += 1024) {
    float v = masked[b * THW + i];
    key[i] = v; kidx[i] = (unsigned short)i;
    if (v != 0.0f) nz++;
  }
  redI[tid] = nz;
  for (int kk = 2; kk <= THW; kk <<= 1) {
    for (int j = kk >> 1; j > 0; j >>= 1) {
      __syncthreads();
      for (int i = tid; i < THW; i += 1024) {
        int l = i ^ j;
        if (l > i) {
          float av = key[i], bv = key[l];
          unsigned short ia = kidx[i], ib = kidx[l];
          bool before = (av > bv) || (av == bv && ia < ib);
          bool up = ((i & kk) == 0);
          if (up ? !before : before) {
            key[i] = bv; key[l] = av; kidx[i] = ib; kidx[l] = ia;
          }
        }
      }
    }
  }
  __syncthreads();
  for (int st = 512; st > 0; st >>= 1) {
    if (tid < st) redI[tid] += redI[tid + st];
    __syncthreads();
  }
  int kcnt = redI[0];
  float kf = (float)kcnt;
  int n_sel = (int)floorf(kf * 0.5f);

  float wsel[4]; int rowv[4]; bool vld[4];
  float ssum = 0.f;
  #pragma unroll
  for (int r = 0; r < 4; r++) {
    int m = tid + r * 1024;
    uint32_t e = (uint32_t)(b * MDRAW + m);
    uint32_t x0 = 0u, x1 = e;
    tf2x32(x0, x1);
    uint32_t bits = x0 ^ x1;
    float u = __uint_as_float((bits >> 9) | 0x3F800000u) - 1.0f;
    int idxd = (int)floorf(u * kf);
    vld[r] = (m < n_sel);
    wsel[r] = (float)(idxd + 1);
    rowv[r] = (int)kidx[idxd < THW ? idxd : (THW - 1)];
    if (vld[r]) ssum += wsel[r];
  }
  redF[tid] = ssum;
  __syncthreads();
  for (int st = 512; st > 0; st >>= 1) {
    if (tid < st) redF[tid] += redF[tid + st];
    __syncthreads();
  }
  float s = redF[0];
  s = (s > 0.f) ? s : 1.0f;
  #pragma unroll
  for (int r = 0; r < 4; r++) {
    if (vld[r]) {
      float wi = wsel[r] * kf / s;
      mult[b * THW + rowv[r]] = wi;
    }
  }
}

// ------- K4: softmax stats (partial max / sumexp per t-chunk) -------
__global__ __launch_bounds__(256) void stats_kernel(const float* __restrict__ mk,
                                                    const float* __restrict__ qk,
                                                    const float* __restrict__ amem,
                                                    const float* __restrict__ mult,
                                                    float* __restrict__ pm,
                                                    float* __restrict__ pl) {
  int b = blockIdx.z, tc = blockIdx.y, qb = blockIdx.x;
  int tid = threadIdx.x;
  int q = qb * 256 + tid;
  __shared__ float mk_sT[64][68];
  __shared__ float am_s[64], mu_s[64];
  float qreg[CK];
  #pragma unroll
  for (int c = 0; c < CK; c++) qreg[c] = qk[((size_t)b * CK + c) * HW + q];

  float m_run = -INFINITY, l_run = 0.f;
  int tbase = tc * (THW / NTC);
  for (int ss = 0; ss < 4; ss++) {
    int t0 = tbase + ss * 64;
    __syncthreads();
    for (int l = tid; l < 64 * 64; l += 256) {
      int c = l >> 6, i = l & 63;
      mk_sT[i][c] = mk[((size_t)b * CK + c) * THW + t0 + i];
    }
    if (tid < 64) {
      am_s[tid] = amem[b * THW + t0 + tid];
      mu_s[tid] = mult[b * THW + t0 + tid];
    }
    __syncthreads();
    for (int t = 0; t < 64; t++) {
      float d = 0.f;
      #pragma unroll
      for (int cc = 0; cc < CK; cc += 4) {
        float4 m4 = *(const float4*)&mk_sT[t][cc];
        d += m4.x * qreg[cc] + m4.y * qreg[cc + 1] + m4.z * qreg[cc + 2] + m4.w * qreg[cc + 3];
      }
      float L = mu_s[t] * ((2.0f * d - am_s[t]) * 0.125f);
      if (L > m_run) { l_run *= expf(m_run - L); m_run = L; }
      l_run += expf(L - m_run);
    }
  }
  int o = (b * HW + q) * NTC + tc;
  pm[o] = m_run; pl[o] = l_run;
}

// ------- K5: combine partial stats -------
__global__ __launch_bounds__(256) void combine_kernel(const float* __restrict__ pm,
                                                      const float* __restrict__ pl,
                                                      float* __restrict__ mfin,
                                                      float* __restrict__ linv) {
  int i = blockIdx.x * 256 + threadIdx.x;
  const float* pmi = pm + (size_t)i * NTC;
  const float* pli = pl + (size_t)i * NTC;
  float m = -INFINITY;
  for (int c = 0; c < NTC; c++) m = fmaxf(m, pmi[c]);
  float l = 0.f;
  for (int c = 0; c < NTC; c++) l += pli[c] * expf(pmi[c] - m);
  mfin[i] = m; linv[i] = 1.0f / l;
}

// ------- K6a: P materialization — logits once, normalize, write f16 P[b][q][t] -------
#define PM_QB 32
#define PM_TC 256
__global__ __launch_bounds__(256) void pmat_kernel(const float* __restrict__ mk,
                                                   const float* __restrict__ qk,
                                                   const float* __restrict__ amem,
                                                   const float* __restrict__ mult,
                                                   const float* __restrict__ mfin,
                                                   const float* __restrict__ linv,
                                                   _Float16* __restrict__ P) {
  int b = blockIdx.z, tc = blockIdx.y, qb = blockIdx.x;
  int tid = threadIdx.x;
  __shared__ float qk_s[CK][PM_QB];      // 8 KB
  __shared__ float mk_sT[64][68];        // 17.4 KB, rows 272B (16B-aligned)
  __shared__ float am_s[64], mu_s[64];
  __shared__ float ms_s[PM_QB], ls_s[PM_QB];
  int q0 = qb * PM_QB;
  for (int l = tid; l < CK * PM_QB; l += 256) {
    int c = l >> 5, q = l & 31;
    qk_s[c][q] = qk[((size_t)b * CK + c) * HW + q0 + q];
  }
  if (tid < PM_QB) {
    ms_s[tid] = mfin[b * HW + q0 + tid];
    ls_s[tid] = linv[b * HW + q0 + tid];
  }
  __syncthreads();
  int qloc = tid >> 3;          // 0..31
  int tj   = tid & 7;           // strided t map: t = i*8 + tj (bank-friendly)
  float qreg[CK];
  #pragma unroll
  for (int c = 0; c < CK; c++) qreg[c] = qk_s[c][qloc];
  float msq = ms_s[qloc], lsq = ls_s[qloc];
  _Float16* prow = P + ((size_t)b * HW + q0 + qloc) * THW;
  int tbase = tc * PM_TC;
  for (int ss = 0; ss < 4; ss++) {
    int t0 = tbase + ss * 64;
    __syncthreads();
    for (int l = tid; l < 64 * 64; l += 256) {
      int c = l >> 6, i = l & 63;
      mk_sT[i][c] = mk[((size_t)b * CK + c) * THW + t0 + i];
    }
    if (tid < 64) {
      am_s[tid] = amem[b * THW + t0 + tid];
      mu_s[tid] = mult[b * THW + t0 + tid];
    }
    __syncthreads();
    #pragma unroll
    for (int i = 0; i < 8; i++) {
      int tl = i * 8 + tj;
      float dd = 0.f;
      #pragma unroll
      for (int cc = 0; cc < CK; cc += 4) {
        float4 m4 = *(const float4*)&mk_sT[tl][cc];
        dd += m4.x * qreg[cc] + m4.y * qreg[cc + 1] + m4.z * qreg[cc + 2] + m4.w * qreg[cc + 3];
      }
      float L = mu_s[tl] * ((2.0f * dd - am_s[tl]) * 0.125f);
      prow[t0 + tl] = (_Float16)(expf(L - msq) * lsq);
    }
  }
}

// ------- K6b: PV GEMM via f16 MFMA: out[c][q] = sum_t mv[c][t] * P[t][q] -------
// grid (qt=16, ct=4, b=4) = 256 blocks, 256 threads (4 waves, 2x2 of 64c x 32q)
#define GM_CT 128
#define GM_QT 64
__global__ __launch_bounds__(256) void pvgemm_kernel(const float* __restrict__ mv,
                                                     const _Float16* __restrict__ P,
                                                     float* __restrict__ out) {
  int b = blockIdx.z, ct = blockIdx.y, qt = blockIdx.x;
  int tid = threadIdx.x;
  __shared__ _Float16 A_h[GM_CT][72];    // 18.4 KB [c][t], rows 144B (16B-aligned)
  __shared__ _Float16 B_h[GM_QT][72];    // 9.2 KB  [q][t]
  int c0 = ct * GM_CT, q0 = qt * GM_QT;
  int w = tid >> 6, lane = tid & 63;
  int wm = w >> 1, wn = w & 1;           // wave sub-tile: 64c x 32q
  f32x4 acc[4][2] = {};                  // 4 c-tiles x 2 q-tiles of 16x16
  const float*    mvb = mv + ((size_t)b * CV + c0) * THW;
  const _Float16* Pb  = P  + ((size_t)b * HW + q0) * THW;

  // staging maps
  int sc = tid >> 1, sth = (tid & 1) * 32;       // A: 128c x 2 halves of 32t
  int sq = tid >> 2, stf = (tid & 3) * 16;       // B: 64q x 4 chunks of 16t

  for (int t0 = 0; t0 < THW; t0 += 64) {
    __syncthreads();
    {   // stage A: mv f32 -> f16
      const float* src = mvb + (size_t)sc * THW + t0 + sth;
      #pragma unroll
      for (int j = 0; j < 4; j++) {
        float4 v0 = *(const float4*)(src + j * 8);
        float4 v1 = *(const float4*)(src + j * 8 + 4);
        union { __half2 h2[4]; float4 f; } u;
        u.h2[0] = __floats2half2_rn(v0.x, v0.y);
        u.h2[1] = __floats2half2_rn(v0.z, v0.w);
        u.h2[2] = __floats2half2_rn(v1.x, v1.y);
        u.h2[3] = __floats2half2_rn(v1.z, v1.w);
        *(float4*)&A_h[sc][sth + j * 8] = u.f;
      }
    }
    {   // stage B: P f16 copy
      const _Float16* srcB = Pb + (size_t)sq * THW + t0 + stf;
      *(float4*)&B_h[sq][stf]     = *(const float4*)srcB;
      *(float4*)&B_h[sq][stf + 8] = *(const float4*)(srcB + 8);
    }
    __syncthreads();
    int cw = wm * 64, qw = wn * 32;
    #pragma unroll
    for (int ks = 0; ks < 2; ks++) {
      int koff = ks * 32 + (lane >> 4) * 8;      // same k-slot map for A and B (cancels)
      half8 bf0 = *(const half8*)&B_h[qw + (lane & 15)][koff];
      half8 bf1 = *(const half8*)&B_h[qw + 16 + (lane & 15)][koff];
      #pragma unroll
      for (int mt = 0; mt < 4; mt++) {
        half8 af = *(const half8*)&A_h[cw + mt * 16 + (lane & 15)][koff];
        acc[mt][0] = __builtin_amdgcn_mfma_f32_16x16x32_f16(af, bf0, acc[mt][0], 0, 0, 0);
        acc[mt][1] = __builtin_amdgcn_mfma_f32_16x16x32_f16(af, bf1, acc[mt][1], 0, 0, 0);
      }
    }
  }
  // epilogue: C/D layout col=lane&15 (q), row=(lane>>4)*4+r (c)  [m89-verified]
  int cw = wm * 64, qw = wn * 32;
  #pragma unroll
  for (int mt = 0; mt < 4; mt++) {
    #pragma unroll
    for (int nt = 0; nt < 2; nt++) {
      int q    = q0 + qw + nt * 16 + (lane & 15);
      int crow = c0 + cw + mt * 16 + (lane >> 4) * 4;
      #pragma unroll
      for (int r = 0; r < 4; r++)
        out[((size_t)b * 1024 + crow + r) * HW + q] = acc[mt][nt][r];
    }
  }
}

// ------- K6 (FALLBACK): fused fp32 pv — used only if ws_size too small -------
#define QT 64
#define CT 128
__global__ __launch_bounds__(512) void pv_kernel(const float* __restrict__ mk,
                                                 const float* __restrict__ qk,
                                                 const float* __restrict__ mv,
                                                 const float* __restrict__ amem,
                                                 const float* __restrict__ mult,
                                                 const float* __restrict__ mfin,
                                                 const float* __restrict__ linv,
                                                 float* __restrict__ out) {
  int b = blockIdx.z, ct = blockIdx.y, qt = blockIdx.x;
  int tid = threadIdx.x;
  __shared__ float qk_s[CK][QT];
  __shared__ float mk_s[CK][64];
  __shared__ float P_s[64][68];
  __shared__ float mv_s[CT][65];
  __shared__ float am_s[64], mu_s[64];
  __shared__ float ms_s[QT], ls_s[QT];

  const int q0blk = qt * QT;
  for (int l = tid; l < CK * QT; l += 512) {
    int c = l / QT, q = l % QT;
    qk_s[c][q] = qk[((size_t)b * CK + c) * HW + q0blk + q];
  }
  if (tid < QT) {
    ms_s[tid] = mfin[b * HW + q0blk + tid];
    ls_s[tid] = linv[b * HW + q0blk + tid];
  }
  float acc[16];
  #pragma unroll
  for (int i = 0; i < 16; i++) acc[i] = 0.f;
  const int tA = tid >> 3, qoA = (tid & 7) * 8;
  const int q0B = (tid & 15) * 4, c0B = (tid >> 4) * 4;
  for (int t0 = 0; t0 < THW; t0 += 64) {
    __syncthreads();
    for (int l = tid; l < CK * 64; l += 512) {
      int c = l >> 6, i = l & 63;
      mk_s[c][i] = mk[((size_t)b * CK + c) * THW + t0 + i];
    }
    for (int l = tid; l < CT * 64; l += 512) {
      int c = l >> 6, i = l & 63;
      mv_s[c][i] = mv[((size_t)b * CV + ct * CT + c) * THW + t0 + i];
    }
    if (tid < 64) {
      am_s[tid] = amem[b * THW + t0 + tid];
      mu_s[tid] = mult[b * THW + t0 + tid];
    }
    __syncthreads();
    {
      float d[8] = {0,0,0,0,0,0,0,0};
      #pragma unroll 16
      for (int c = 0; c < CK; c++) {
        float mkv = mk_s[c][tA];
        float4 qa = *(const float4*)&qk_s[c][qoA];
        float4 qb = *(const float4*)&qk_s[c][qoA + 4];
        d[0] += mkv * qa.x; d[1] += mkv * qa.y; d[2] += mkv * qa.z; d[3] += mkv * qa.w;
        d[4] += mkv * qb.x; d[5] += mkv * qb.y; d[6] += mkv * qb.z; d[7] += mkv * qb.w;
      }
      float a = am_s[tA], mu = mu_s[tA];
      float4 pA, pB;
      float L;
      L = mu * ((2.0f*d[0] - a) * 0.125f); pA.x = expf(L - ms_s[qoA+0]) * ls_s[qoA+0];
      L = mu * ((2.0f*d[1] - a) * 0.125f); pA.y = expf(L - ms_s[qoA+1]) * ls_s[qoA+1];
      L = mu * ((2.0f*d[2] - a) * 0.125f); pA.z = expf(L - ms_s[qoA+2]) * ls_s[qoA+2];
      L = mu * ((2.0f*d[3] - a) * 0.125f); pA.w = expf(L - ms_s[qoA+3]) * ls_s[qoA+3];
      L = mu * ((2.0f*d[4] - a) * 0.125f); pB.x = expf(L - ms_s[qoA+4]) * ls_s[qoA+4];
      L = mu * ((2.0f*d[5] - a) * 0.125f); pB.y = expf(L - ms_s[qoA+5]) * ls_s[qoA+5];
      L = mu * ((2.0f*d[6] - a) * 0.125f); pB.z = expf(L - ms_s[qoA+6]) * ls_s[qoA+6];
      L = mu * ((2.0f*d[7] - a) * 0.125f); pB.w = expf(L - ms_s[qoA+7]) * ls_s[qoA+7];
      *(float4*)&P_s[tA][qoA]     = pA;
      *(float4*)&P_s[tA][qoA + 4] = pB;
    }
    __syncthreads();
    #pragma unroll 8
    for (int t = 0; t < 64; t++) {
      float4 p4 = *(const float4*)&P_s[t][q0B];
      float m0 = mv_s[c0B + 0][t];
      float m1 = mv_s[c0B + 1][t];
      float m2 = mv_s[c0B + 2][t];
      float m3 = mv_s[c0B + 3][t];
      acc[0]  += m0 * p4.x; acc[1]  += m0 * p4.y; acc[2]  += m0 * p4.z; acc[3]  += m0 * p4.w;
      acc[4]  += m1 * p4.x; acc[5]  += m1 * p4.y; acc[6]  += m1 * p4.z; acc[7]  += m1 * p4.w;
      acc[8]  += m2 * p4.x; acc[9]  += m2 * p4.y; acc[10] += m2 * p4.z; acc[11] += m2 * p4.w;
      acc[12] += m3 * p4.x; acc[13] += m3 * p4.y; acc[14] += m3 * p4.z; acc[15] += m3 * p4.w;
    }
  }
  #pragma unroll
  for (int i = 0; i < 4; i++) {
    float4 o4 = make_float4(acc[i*4+0], acc[i*4+1], acc[i*4+2], acc[i*4+3]);
    *(float4*)&out[((size_t)b * 1024 + ct * CT + c0B + i) * HW + q0blk + q0B] = o4;
  }
}

// ------- K7: qv passthrough into out[:, 512:1024] -------
__global__ __launch_bounds__(256) void qvcopy_kernel(const float* __restrict__ qv,
                                                     float* __restrict__ out) {
  int i = blockIdx.x * 256 + threadIdx.x;
  const float4* src = (const float4*)qv;
  float4* dst = (float4*)out;
  int q4 = i & 255;
  int c = (i >> 8) & 511;
  int b = i >> 17;
  dst[((size_t)(b * 1024 + 512 + c) << 8) + q4] = src[i];
}

extern "C" void kernel_launch(void* const* d_in, const int* in_sizes, int n_in,
                              void* d_out, int out_size, void* d_ws, size_t ws_size,
                              hipStream_t stream) {
  (void)in_sizes; (void)n_in; (void)out_size;
  const float* mk   = (const float*)d_in[0];
  const float* qk   = (const float*)d_in[1];
  const float* mv   = (const float*)d_in[2];
  const float* qv   = (const float*)d_in[3];
  const float* mask = (const float*)d_in[4];
  float* out = (float*)d_out;
  float* W = (float*)d_ws;

  float* qkbar  = W + OFF_QKBAR;
  float* amem   = W + OFF_A;
  float* masked = W + OFF_MASK;
  float* mult   = W + OFF_MULT;
  float* pm     = W + OFF_PM;
  float* pl     = W + OFF_PL;
  float* mfin   = W + OFF_MF;
  float* linv   = W + OFF_LI;
  _Float16* Pbuf = (_Float16*)((char*)d_ws + OFF_P_BYTES);

  qkbar_kernel<<<NB * CK, 256, 0, stream>>>(qk, qkbar);
  support_kernel<<<dim3(THW / 256, NB), 256, 0, stream>>>(mk, mask, qkbar, amem, masked, mult);
  sort_realloc_kernel<<<NB, 1024, 0, stream>>>(masked, mult);
  stats_kernel<<<dim3(HW / 256, NTC, NB), 256, 0, stream>>>(mk, qk, amem, mult, pm, pl);
  combine_kernel<<<NB * HW / 256, 256, 0, stream>>>(pm, pl, mfin, linv);
  if (ws_size >= WS_NEED) {
    pmat_kernel<<<dim3(HW / PM_QB, THW / PM_TC, NB), 256, 0, stream>>>(mk, qk, amem, mult, mfin, linv, Pbuf);
    pvgemm_kernel<<<dim3(HW / GM_QT, CV / GM_CT, NB), 256, 0, stream>>>(mv, Pbuf, out);
  } else {
    pv_kernel<<<dim3(HW / QT, CV / CT, NB), 512, 0, stream>>>(mk, qk, mv, amem, mult, mfin, linv, out);
  }
  qvcopy_kernel<<<NB * CV * HW / 4 / 256, 256, 0, stream>>>(qv, out);
}

// Round 8
// 636.817 us; speedup vs baseline: 2.2866x; 1.2657x over previous
//
#include <hip/hip_runtime.h>
#include <hip/hip_fp16.h>
#include <stdint.h>
#include <math.h>

// Problem constants (B, CK, CV, T, H, W) = (4, 64, 512, 8, 32, 32)
#define NB   4
#define CK   64
#define CV   512
#define THW  8192
#define HW   1024
#define MDRAW 4096   // floor(THW * 0.5)
#define NTC  32      // t-chunks for stats pass

// ---- ws layout (float offsets) ----
#define OFF_QKBAR 0
#define OFF_A     (OFF_QKBAR + NB*CK)
#define OFF_MASK  (OFF_A + NB*THW)
#define OFF_MULT  (OFF_MASK + NB*THW)
#define OFF_PM    (OFF_MULT + NB*THW)
#define OFF_PL    (OFF_PM + NB*HW*NTC)
#define OFF_MF    (OFF_PL + NB*HW*NTC)
#define OFF_LI    (OFF_MF + NB*HW)
#define WS_FLOATS (OFF_LI + NB*HW)
#define OFF_P_BYTES ((size_t)WS_FLOATS * 4)
#define P_BYTES   ((size_t)NB * HW * THW * 2)          // 64 MiB f16
#define WS_NEED   (OFF_P_BYTES + P_BYTES)

typedef _Float16 half8 __attribute__((ext_vector_type(8)));
typedef float f32x4 __attribute__((ext_vector_type(4)));

// ---------------- K1: qkbar ----------------
__global__ __launch_bounds__(256) void qkbar_kernel(const float* __restrict__ qk,
                                                    float* __restrict__ qkbar) {
  int bc = blockIdx.x;
  const float4* src = (const float4*)(qk + (size_t)bc * HW);
  float4 v = src[threadIdx.x];
  double s = (double)v.x + (double)v.y + (double)v.z + (double)v.w;
  __shared__ double red[256];
  red[threadIdx.x] = s; __syncthreads();
  for (int st = 128; st > 0; st >>= 1) {
    if (threadIdx.x < st) red[threadIdx.x] += red[threadIdx.x + st];
    __syncthreads();
  }
  if (threadIdx.x == 0) qkbar[bc] = (float)(red[0] * (1.0 / 1024.0));
}

// ------- K2: support -------
__global__ __launch_bounds__(256) void support_kernel(const float* __restrict__ mk,
                                                      const float* __restrict__ mask,
                                                      const float* __restrict__ qkbar,
                                                      float* __restrict__ amem,
                                                      float* __restrict__ masked,
                                                      float* __restrict__ mult) {
  int b = blockIdx.y;
  int t = blockIdx.x * 256 + threadIdx.x;
  __shared__ float qb[CK];
  if (threadIdx.x < CK) qb[threadIdx.x] = qkbar[b * CK + threadIdx.x];
  __syncthreads();
  const float* mkp = mk + (size_t)b * CK * THW + t;
  double a = 0.0, d = 0.0;
  #pragma unroll
  for (int c = 0; c < CK; c++) {
    double v = (double)mkp[(size_t)c * THW];
    a += v * v;
    d += v * (double)qb[c];
  }
  double sup = (2.0 * d - a) * 0.125;
  amem[b * THW + t] = (float)a;
  float mval = mask[b * THW + t];
  masked[b * THW + t] = (mval > 0.5f) ? (float)sup : 0.0f;
  mult[b * THW + t] = 1.0f;
}

// ---------------- Threefry-2x32-20, key = (0, 1234) ----------------
__device__ __forceinline__ uint32_t rotl32(uint32_t v, int d) {
  return (v << d) | (v >> (32 - d));
}
__device__ __forceinline__ void tf2x32(uint32_t& x0, uint32_t& x1) {
  const uint32_t ks0 = 0u, ks1 = 1234u;
  const uint32_t ks2 = ks0 ^ ks1 ^ 0x1BD11BDAu;
  x0 += ks0; x1 += ks1;
#define TF_R4(ra,rb,rc,rd) \
  x0 += x1; x1 = rotl32(x1, ra); x1 ^= x0; \
  x0 += x1; x1 = rotl32(x1, rb); x1 ^= x0; \
  x0 += x1; x1 = rotl32(x1, rc); x1 ^= x0; \
  x0 += x1; x1 = rotl32(x1, rd); x1 ^= x0;
  TF_R4(13,15,26,6);  x0 += ks1; x1 += ks2 + 1u;
  TF_R4(17,29,16,24); x0 += ks2; x1 += ks0 + 2u;
  TF_R4(13,15,26,6);  x0 += ks0; x1 += ks1 + 3u;
  TF_R4(17,29,16,24); x0 += ks1; x1 += ks2 + 4u;
  TF_R4(13,15,26,6);  x0 += ks2; x1 += ks0 + 5u;
#undef TF_R4
}

// ------- K3: sort + reallocate (threefry partitionable mode: x=(0,e), bits=out0^out1) -------
__global__ __launch_bounds__(1024) void sort_realloc_kernel(const float* __restrict__ masked,
                                                            float* __restrict__ mult) {
  int b = blockIdx.x;
  int tid = threadIdx.x;
  __shared__ float key[THW];
  __shared__ unsigned short kidx[THW];
  __shared__ float redF[1024];
  __shared__ int   redI[1024];

  int nz = 0;
  for (int i = tid; i < THW; i += 1024) {
    float v = masked[b * THW + i];
    key[i] = v; kidx[i] = (unsigned short)i;
    if (v != 0.0f) nz++;
  }
  redI[tid] = nz;
  for (int kk = 2; kk <= THW; kk <<= 1) {
    for (int j = kk >> 1; j > 0; j >>= 1) {
      __syncthreads();
      for (int i = tid; i < THW; i += 1024) {
        int l = i ^ j;
        if (l > i) {
          float av = key[i], bv = key[l];
          unsigned short ia = kidx[i], ib = kidx[l];
          bool before = (av > bv) || (av == bv && ia < ib);
          bool up = ((i & kk) == 0);
          if (up ? !before : before) {
            key[i] = bv; key[l] = av; kidx[i] = ib; kidx[l] = ia;
          }
        }
      }
    }
  }
  __syncthreads();
  for (int st = 512; st > 0; st >>= 1) {
    if (tid < st) redI[tid] += redI[tid + st];
    __syncthreads();
  }
  int kcnt = redI[0];
  float kf = (float)kcnt;
  int n_sel = (int)floorf(kf * 0.5f);

  float wsel[4]; int rowv[4]; bool vld[4];
  float ssum = 0.f;
  #pragma unroll
  for (int r = 0; r < 4; r++) {
    int m = tid + r * 1024;
    uint32_t e = (uint32_t)(b * MDRAW + m);
    uint32_t x0 = 0u, x1 = e;
    tf2x32(x0, x1);
    uint32_t bits = x0 ^ x1;
    float u = __uint_as_float((bits >> 9) | 0x3F800000u) - 1.0f;
    int idxd = (int)floorf(u * kf);
    vld[r] = (m < n_sel);
    wsel[r] = (float)(idxd + 1);
    rowv[r] = (int)kidx[idxd < THW ? idxd : (THW - 1)];
    if (vld[r]) ssum += wsel[r];
  }
  redF[tid] = ssum;
  __syncthreads();
  for (int st = 512; st > 0; st >>= 1) {
    if (tid < st) redF[tid] += redF[tid + st];
    __syncthreads();
  }
  float s = redF[0];
  s = (s > 0.f) ? s : 1.0f;
  #pragma unroll
  for (int r = 0; r < 4; r++) {
    if (vld[r]) {
      float wi = wsel[r] * kf / s;
      mult[b * THW + rowv[r]] = wi;
    }
  }
}

// ------- K4: softmax stats -------
__global__ __launch_bounds__(256) void stats_kernel(const float* __restrict__ mk,
                                                    const float* __restrict__ qk,
                                                    const float* __restrict__ amem,
                                                    const float* __restrict__ mult,
                                                    float* __restrict__ pm,
                                                    float* __restrict__ pl) {
  int b = blockIdx.z, tc = blockIdx.y, qb = blockIdx.x;
  int tid = threadIdx.x;
  int q = qb * 256 + tid;
  __shared__ float mk_sT[64][68];
  __shared__ float am_s[64], mu_s[64];
  float qreg[CK];
  #pragma unroll
  for (int c = 0; c < CK; c++) qreg[c] = qk[((size_t)b * CK + c) * HW + q];

  float m_run = -INFINITY, l_run = 0.f;
  int tbase = tc * (THW / NTC);
  for (int ss = 0; ss < 4; ss++) {
    int t0 = tbase + ss * 64;
    __syncthreads();
    for (int l = tid; l < 64 * 64; l += 256) {
      int c = l >> 6, i = l & 63;
      mk_sT[i][c] = mk[((size_t)b * CK + c) * THW + t0 + i];
    }
    if (tid < 64) {
      am_s[tid] = amem[b * THW + t0 + tid];
      mu_s[tid] = mult[b * THW + t0 + tid];
    }
    __syncthreads();
    for (int t = 0; t < 64; t++) {
      float d = 0.f;
      #pragma unroll
      for (int cc = 0; cc < CK; cc += 4) {
        float4 m4 = *(const float4*)&mk_sT[t][cc];
        d += m4.x * qreg[cc] + m4.y * qreg[cc + 1] + m4.z * qreg[cc + 2] + m4.w * qreg[cc + 3];
      }
      float L = mu_s[t] * ((2.0f * d - am_s[t]) * 0.125f);
      if (L > m_run) { l_run *= expf(m_run - L); m_run = L; }
      l_run += expf(L - m_run);
    }
  }
  int o = (b * HW + q) * NTC + tc;
  pm[o] = m_run; pl[o] = l_run;
}

// ------- K5: combine -------
__global__ __launch_bounds__(256) void combine_kernel(const float* __restrict__ pm,
                                                      const float* __restrict__ pl,
                                                      float* __restrict__ mfin,
                                                      float* __restrict__ linv) {
  int i = blockIdx.x * 256 + threadIdx.x;
  const float* pmi = pm + (size_t)i * NTC;
  const float* pli = pl + (size_t)i * NTC;
  float m = -INFINITY;
  for (int c = 0; c < NTC; c++) m = fmaxf(m, pmi[c]);
  float l = 0.f;
  for (int c = 0; c < NTC; c++) l += pli[c] * expf(pmi[c] - m);
  mfin[i] = m; linv[i] = 1.0f / l;
}

// ------- K6a: pmat2 — QK^T logits via MFMA, normalize, write f16 P[b][q][t] -------
// grid (16 qb, 32 tc, 4 b) = 2048 blocks, 256 thr (4 waves; wave w -> q-block w*16)
#define P2_QB 64
#define P2_TC 256
__global__ __launch_bounds__(256) void pmat2_kernel(const float* __restrict__ mk,
                                                    const float* __restrict__ qk,
                                                    const float* __restrict__ amem,
                                                    const float* __restrict__ mult,
                                                    const float* __restrict__ mfin,
                                                    const float* __restrict__ linv,
                                                    _Float16* __restrict__ P) {
  int b = blockIdx.z, tc = blockIdx.y, qb = blockIdx.x;
  int tid = threadIdx.x;
  __shared__ _Float16 qk_s[P2_QB][72];   // [q][c], rows 144B -> 2-way-free banks
  __shared__ _Float16 mk_sT[64][72];     // [t][c] per 64-t subtile
  __shared__ float am_s[P2_TC], mu_s[P2_TC];
  __shared__ float ms_s[P2_QB], ls_s[P2_QB];
  int q0 = qb * P2_QB, tbase = tc * P2_TC;

  { // stage qk tile [64c][64q] f32 -> qk_s[q][c] f16 (once)
    int c = tid >> 2, qc = (tid & 3) * 16;
    const float* src = qk + ((size_t)b * CK + c) * HW + q0 + qc;
    #pragma unroll
    for (int j = 0; j < 4; j++) {
      float4 v = *(const float4*)(src + j * 4);
      qk_s[qc + j*4 + 0][c] = (_Float16)v.x;
      qk_s[qc + j*4 + 1][c] = (_Float16)v.y;
      qk_s[qc + j*4 + 2][c] = (_Float16)v.z;
      qk_s[qc + j*4 + 3][c] = (_Float16)v.w;
    }
  }
  am_s[tid] = amem[b * THW + tbase + tid];
  mu_s[tid] = mult[b * THW + tbase + tid];
  if (tid < P2_QB) {
    ms_s[tid] = mfin[b * HW + q0 + tid];
    ls_s[tid] = linv[b * HW + q0 + tid];
  }

  int w = tid >> 6, lane = tid & 63;
  int g = lane >> 4;
  int qwl = w * 16 + (lane & 15);        // this lane's q (column)

  for (int ss = 0; ss < 4; ss++) {
    __syncthreads();                     // prev reads of mk_sT done; staged data visible
    int t0 = tbase + ss * 64;
    { // stage mk [64c][64t] f32 -> mk_sT[t][c] f16
      int c = tid >> 2, t4 = (tid & 3) * 16;
      const float* src = mk + ((size_t)b * CK + c) * THW + t0 + t4;
      #pragma unroll
      for (int j = 0; j < 4; j++) {
        float4 v = *(const float4*)(src + j * 4);
        mk_sT[t4 + j*4 + 0][c] = (_Float16)v.x;
        mk_sT[t4 + j*4 + 1][c] = (_Float16)v.y;
        mk_sT[t4 + j*4 + 2][c] = (_Float16)v.z;
        mk_sT[t4 + j*4 + 3][c] = (_Float16)v.w;
      }
    }
    __syncthreads();
    f32x4 acc[4] = {};
    #pragma unroll
    for (int ks = 0; ks < 2; ks++) {
      int koff = ks * 32 + g * 8;
      half8 bf = *(const half8*)&qk_s[qwl][koff];
      #pragma unroll
      for (int mt = 0; mt < 4; mt++) {
        half8 af = *(const half8*)&mk_sT[mt * 16 + (lane & 15)][koff];
        acc[mt] = __builtin_amdgcn_mfma_f32_16x16x32_f16(af, bf, acc[mt], 0, 0, 0);
      }
    }
    // epilogue: D row = t = mt*16 + g*4 + r, col = q = qwl  [validated convention]
    float msq = ms_s[qwl], lsq = ls_s[qwl];
    _Float16* prow = P + ((size_t)b * HW + q0 + qwl) * THW;
    #pragma unroll
    for (int mt = 0; mt < 4; mt++) {
      int tl = mt * 16 + g * 4;
      union { _Float16 h[4]; uint2 u; } pk;
      #pragma unroll
      for (int r = 0; r < 4; r++) {
        int t = ss * 64 + tl + r;        // chunk-local index
        float S = acc[mt][r];
        float L = mu_s[t] * ((2.0f * S - am_s[t]) * 0.125f);
        pk.h[r] = (_Float16)(expf(L - msq) * lsq);
      }
      *(uint2*)&prow[t0 + tl] = pk.u;
    }
  }
}

// ------- zero the mem half of out (atomic accumulation target) -------
__global__ __launch_bounds__(256) void zero_mem_kernel(float* __restrict__ out) {
  int i = blockIdx.x * 256 + threadIdx.x;     // 524288 float4s = 8.4 MB
  int q4 = i & 255;
  int c = (i >> 8) & 511;
  int b = i >> 17;
  ((float4*)out)[((size_t)(b * 1024 + c) << 8) + q4] = make_float4(0.f, 0.f, 0.f, 0.f);
}

// ------- K6b: pvgemm2 — f16 MFMA PV with k-split + reg-prefetch -------
// tile 128c x 128q, K-step 64, ksplit 4. grid (8 qt, 4 ct, 16 b*ks) = 512 blocks, 512 thr (8 waves 2x4)
#define G2_CT 128
#define G2_QT 128
#define G2_KS 4
__global__ __launch_bounds__(512) void pvgemm2_kernel(const float* __restrict__ mv,
                                                      const _Float16* __restrict__ P,
                                                      float* __restrict__ out) {
  int bz = blockIdx.z;
  int b = bz >> 2, ksl = bz & 3;
  int ct = blockIdx.y, qt = blockIdx.x;
  int tid = threadIdx.x;
  __shared__ _Float16 A_h[G2_CT][72];    // [c][t] 18.4 KB
  __shared__ _Float16 B_h[G2_QT][72];    // [q][t] 18.4 KB
  int c0 = ct * G2_CT, q0 = qt * G2_QT;
  int w = tid >> 6, lane = tid & 63;
  int wm = w >> 2, wn = w & 3;
  int cw = wm * 64, qw = wn * 32;
  f32x4 acc[4][2] = {};
  const float*    mvb = mv + ((size_t)b * CV + c0) * THW;
  const _Float16* Pb  = P  + ((size_t)b * HW + q0) * THW;

  int sc = tid >> 2, st4 = (tid & 3) * 16;   // both A (c-rows) and B (q-rows): 128 rows x 16 t
  const int tstart = ksl * (THW / G2_KS);
  const int NIT = (THW / G2_KS) / 64;        // 32

  float4 arg[4]; float4 brg[2];
  { // prologue loads
    const float* sA = mvb + (size_t)sc * THW + tstart + st4;
    arg[0] = *(const float4*)(sA);     arg[1] = *(const float4*)(sA + 4);
    arg[2] = *(const float4*)(sA + 8); arg[3] = *(const float4*)(sA + 12);
    const _Float16* sB = Pb + (size_t)sc * THW + tstart + st4;
    brg[0] = *(const float4*)(sB); brg[1] = *(const float4*)(sB + 8);
  }

  for (int it = 0; it < NIT; ++it) {
    { // write staged tile (prev reads finished at trailing barrier)
      union { __half2 h2[4]; float4 f; } u;
      u.h2[0] = __floats2half2_rn(arg[0].x, arg[0].y);
      u.h2[1] = __floats2half2_rn(arg[0].z, arg[0].w);
      u.h2[2] = __floats2half2_rn(arg[1].x, arg[1].y);
      u.h2[3] = __floats2half2_rn(arg[1].z, arg[1].w);
      *(float4*)&A_h[sc][st4] = u.f;
      u.h2[0] = __floats2half2_rn(arg[2].x, arg[2].y);
      u.h2[1] = __floats2half2_rn(arg[2].z, arg[2].w);
      u.h2[2] = __floats2half2_rn(arg[3].x, arg[3].y);
      u.h2[3] = __floats2half2_rn(arg[3].z, arg[3].w);
      *(float4*)&A_h[sc][st4 + 8] = u.f;
      *(float4*)&B_h[sc][st4]     = brg[0];
      *(float4*)&B_h[sc][st4 + 8] = brg[1];
    }
    if (it + 1 < NIT) { // issue next loads; in flight across barriers + MFMA
      int t0 = tstart + (it + 1) * 64;
      const float* sA = mvb + (size_t)sc * THW + t0 + st4;
      arg[0] = *(const float4*)(sA);     arg[1] = *(const float4*)(sA + 4);
      arg[2] = *(const float4*)(sA + 8); arg[3] = *(const float4*)(sA + 12);
      const _Float16* sB = Pb + (size_t)sc * THW + t0 + st4;
      brg[0] = *(const float4*)(sB); brg[1] = *(const float4*)(sB + 8);
    }
    __syncthreads();
    #pragma unroll
    for (int ks = 0; ks < 2; ks++) {
      int koff = ks * 32 + (lane >> 4) * 8;
      half8 bf0 = *(const half8*)&B_h[qw + (lane & 15)][koff];
      half8 bf1 = *(const half8*)&B_h[qw + 16 + (lane & 15)][koff];
      #pragma unroll
      for (int mt = 0; mt < 4; mt++) {
        half8 af = *(const half8*)&A_h[cw + mt * 16 + (lane & 15)][koff];
        acc[mt][0] = __builtin_amdgcn_mfma_f32_16x16x32_f16(af, bf0, acc[mt][0], 0, 0, 0);
        acc[mt][1] = __builtin_amdgcn_mfma_f32_16x16x32_f16(af, bf1, acc[mt][1], 0, 0, 0);
      }
    }
    __syncthreads();
  }
  // epilogue: atomic accumulate partials (out pre-zeroed)
  #pragma unroll
  for (int mt = 0; mt < 4; mt++) {
    #pragma unroll
    for (int nt = 0; nt < 2; nt++) {
      int q    = q0 + qw + nt * 16 + (lane & 15);
      int crow = c0 + cw + mt * 16 + (lane >> 4) * 4;
      #pragma unroll
      for (int r = 0; r < 4; r++)
        unsafeAtomicAdd(&out[((size_t)b * 1024 + crow + r) * HW + q], acc[mt][nt][r]);
    }
  }
}

// ------- K6 (FALLBACK): fused fp32 pv — only if ws too small -------
#define QT 64
#define CT 128
__global__ __launch_bounds__(512) void pv_kernel(const float* __restrict__ mk,
                                                 const float* __restrict__ qk,
                                                 const float* __restrict__ mv,
                                                 const float* __restrict__ amem,
                                                 const float* __restrict__ mult,
                                                 const float* __restrict__ mfin,
                                                 const float* __restrict__ linv,
                                                 float* __restrict__ out) {
  int b = blockIdx.z, ct = blockIdx.y, qt = blockIdx.x;
  int tid = threadIdx.x;
  __shared__ float qk_s[CK][QT];
  __shared__ float mk_s[CK][64];
  __shared__ float P_s[64][68];
  __shared__ float mv_s[CT][65];
  __shared__ float am_s[64], mu_s[64];
  __shared__ float ms_s[QT], ls_s[QT];
  const int q0blk = qt * QT;
  for (int l = tid; l < CK * QT; l += 512) {
    int c = l / QT, q = l % QT;
    qk_s[c][q] = qk[((size_t)b * CK + c) * HW + q0blk + q];
  }
  if (tid < QT) {
    ms_s[tid] = mfin[b * HW + q0blk + tid];
    ls_s[tid] = linv[b * HW + q0blk + tid];
  }
  float acc[16];
  #pragma unroll
  for (int i = 0; i < 16; i++) acc[i] = 0.f;
  const int tA = tid >> 3, qoA = (tid & 7) * 8;
  const int q0B = (tid & 15) * 4, c0B = (tid >> 4) * 4;
  for (int t0 = 0; t0 < THW; t0 += 64) {
    __syncthreads();
    for (int l = tid; l < CK * 64; l += 512) {
      int c = l >> 6, i = l & 63;
      mk_s[c][i] = mk[((size_t)b * CK + c) * THW + t0 + i];
    }
    for (int l = tid; l < CT * 64; l += 512) {
      int c = l >> 6, i = l & 63;
      mv_s[c][i] = mv[((size_t)b * CV + ct * CT + c) * THW + t0 + i];
    }
    if (tid < 64) {
      am_s[tid] = amem[b * THW + t0 + tid];
      mu_s[tid] = mult[b * THW + t0 + tid];
    }
    __syncthreads();
    {
      float d[8] = {0,0,0,0,0,0,0,0};
      #pragma unroll 16
      for (int c = 0; c < CK; c++) {
        float mkv = mk_s[c][tA];
        float4 qa = *(const float4*)&qk_s[c][qoA];
        float4 qb = *(const float4*)&qk_s[c][qoA + 4];
        d[0] += mkv * qa.x; d[1] += mkv * qa.y; d[2] += mkv * qa.z; d[3] += mkv * qa.w;
        d[4] += mkv * qb.x; d[5] += mkv * qb.y; d[6] += mkv * qb.z; d[7] += mkv * qb.w;
      }
      float a = am_s[tA], mu = mu_s[tA];
      float4 pA, pB;
      float L;
      L = mu * ((2.0f*d[0] - a) * 0.125f); pA.x = expf(L - ms_s[qoA+0]) * ls_s[qoA+0];
      L = mu * ((2.0f*d[1] - a) * 0.125f); pA.y = expf(L - ms_s[qoA+1]) * ls_s[qoA+1];
      L = mu * ((2.0f*d[2] - a) * 0.125f); pA.z = expf(L - ms_s[qoA+2]) * ls_s[qoA+2];
      L = mu * ((2.0f*d[3] - a) * 0.125f); pA.w = expf(L - ms_s[qoA+3]) * ls_s[qoA+3];
      L = mu * ((2.0f*d[4] - a) * 0.125f); pB.x = expf(L - ms_s[qoA+4]) * ls_s[qoA+4];
      L = mu * ((2.0f*d[5] - a) * 0.125f); pB.y = expf(L - ms_s[qoA+5]) * ls_s[qoA+5];
      L = mu * ((2.0f*d[6] - a) * 0.125f); pB.z = expf(L - ms_s[qoA+6]) * ls_s[qoA+6];
      L = mu * ((2.0f*d[7] - a) * 0.125f); pB.w = expf(L - ms_s[qoA+7]) * ls_s[qoA+7];
      *(float4*)&P_s[tA][qoA]     = pA;
      *(float4*)&P_s[tA][qoA + 4] = pB;
    }
    __syncthreads();
    #pragma unroll 8
    for (int t = 0; t < 64; t++) {
      float4 p4 = *(const float4*)&P_s[t][q0B];
      float m0 = mv_s[c0B + 0][t];
      float m1 = mv_s[c0B + 1][t];
      float m2 = mv_s[c0B + 2][t];
      float m3 = mv_s[c0B + 3][t];
      acc[0]  += m0 * p4.x; acc[1]  += m0 * p4.y; acc[2]  += m0 * p4.z; acc[3]  += m0 * p4.w;
      acc[4]  += m1 * p4.x; acc[5]  += m1 * p4.y; acc[6]  += m1 * p4.z; acc[7]  += m1 * p4.w;
      acc[8]  += m2 * p4.x; acc[9]  += m2 * p4.y; acc[10] += m2 * p4.z; acc[11] += m2 * p4.w;
      acc[12] += m3 * p4.x; acc[13] += m3 * p4.y; acc[14] += m3 * p4.z; acc[15] += m3 * p4.w;
    }
  }
  #pragma unroll
  for (int i = 0; i < 4; i++) {
    float4 o4 = make_float4(acc[i*4+0], acc[i*4+1], acc[i*4+2], acc[i*4+3]);
    *(float4*)&out[((size_t)b * 1024 + ct * CT + c0B + i) * HW + q0blk + q0B] = o4;
  }
}

// ------- K7: qv passthrough -------
__global__ __launch_bounds__(256) void qvcopy_kernel(const float* __restrict__ qv,
                                                     float* __restrict__ out) {
  int i = blockIdx.x * 256 + threadIdx.x;
  const float4* src = (const float4*)qv;
  float4* dst = (float4*)out;
  int q4 = i & 255;
  int c = (i >> 8) & 511;
  int b = i >> 17;
  dst[((size_t)(b * 1024 + 512 + c) << 8) + q4] = src[i];
}

extern "C" void kernel_launch(void* const* d_in, const int* in_sizes, int n_in,
                              void* d_out, int out_size, void* d_ws, size_t ws_size,
                              hipStream_t stream) {
  (void)in_sizes; (void)n_in; (void)out_size;
  const float* mk   = (const float*)d_in[0];
  const float* qk   = (const float*)d_in[1];
  const float* mv   = (const float*)d_in[2];
  const float* qv   = (const float*)d_in[3];
  const float* mask = (const float*)d_in[4];
  float* out = (float*)d_out;
  float* W = (float*)d_ws;

  float* qkbar  = W + OFF_QKBAR;
  float* amem   = W + OFF_A;
  float* masked = W + OFF_MASK;
  float* mult   = W + OFF_MULT;
  float* pm     = W + OFF_PM;
  float* pl     = W + OFF_PL;
  float* mfin   = W + OFF_MF;
  float* linv   = W + OFF_LI;
  _Float16* Pbuf = (_Float16*)((char*)d_ws + OFF_P_BYTES);

  qkbar_kernel<<<NB * CK, 256, 0, stream>>>(qk, qkbar);
  support_kernel<<<dim3(THW / 256, NB), 256, 0, stream>>>(mk, mask, qkbar, amem, masked, mult);
  sort_realloc_kernel<<<NB, 1024, 0, stream>>>(masked, mult);
  stats_kernel<<<dim3(HW / 256, NTC, NB), 256, 0, stream>>>(mk, qk, amem, mult, pm, pl);
  combine_kernel<<<NB * HW / 256, 256, 0, stream>>>(pm, pl, mfin, linv);
  if (ws_size >= WS_NEED) {
    pmat2_kernel<<<dim3(HW / P2_QB, THW / P2_TC, NB), 256, 0, stream>>>(mk, qk, amem, mult, mfin, linv, Pbuf);
    zero_mem_kernel<<<2048, 256, 0, stream>>>(out);
    pvgemm2_kernel<<<dim3(HW / G2_QT, CV / G2_CT, NB * G2_KS), 512, 0, stream>>>(mv, Pbuf, out);
  } else {
    pv_kernel<<<dim3(HW / QT, CV / CT, NB), 512, 0, stream>>>(mk, qk, mv, amem, mult, mfin, linv, out);
  }
  qvcopy_kernel<<<NB * CV * HW / 4 / 256, 256, 0, stream>>>(qv, out);
}